// Round 13
// baseline (132.739 us; speedup 1.0000x reference)
//
#include <hip/hip_runtime.h>
#include <hip/hip_bf16.h>

// Shapes (fixed): B=2048, S=50, D=128, H=8, L=128, HL=1024.
// R13 = R12 + 2-tile software pipeline in fused loop: iteration t issues
// MFMA(t+1) into the alternate accumulator BEFORE post-processing tile t's
// sigmoid/softmax -> trans/VALU work overlaps matrix-pipe execution.
// kw moved back to LDS (51200 B has same occupancy as 49152, frees 16 regs
// to pay for the second accumulator set; total ~156 regs unchanged).

typedef _Float16 f16x8 __attribute__((ext_vector_type(8)));
typedef float f32x4 __attribute__((ext_vector_type(4)));

#define LOG2E 1.44269504088896340736f

__device__ __forceinline__ unsigned short f2h(float f) {
  _Float16 h = (_Float16)f;
  return __builtin_bit_cast(unsigned short, h);
}
__device__ __forceinline__ float h2f(unsigned short s) {
  return (float)__builtin_bit_cast(_Float16, s);
}
__device__ __forceinline__ float fexp2(float x) {
#if __has_builtin(__builtin_amdgcn_exp2f)
  return __builtin_amdgcn_exp2f(x);
#else
  return exp2f(x);
#endif
}
__device__ __forceinline__ float frcp(float x) {
#if __has_builtin(__builtin_amdgcn_rcpf)
  return __builtin_amdgcn_rcpf(x);
#else
  return 1.0f / x;
#endif
}
__device__ __forceinline__ float sig_scaled(float a) {  // a = -log2e * z
  return frcp(1.0f + fexp2(a));
}

// async global -> LDS, 16B per lane; lds dest must be wave-uniform base.
__device__ __forceinline__ void dma16(const void* g, void* l) {
  __builtin_amdgcn_global_load_lds(
      (const __attribute__((address_space(1))) unsigned int*)g,
      (__attribute__((address_space(3))) unsigned int*)(unsigned int)(unsigned long long)l,
      16, 0, 0);
}

// ---------------------------------------------------------------------------
// prep: ws16 layout (elements):
//   [0]       WqS  swizzled-tile layout (64 tiles x 2048 elems)
//   [131072]  WkT  linear [n][d] (for kw_kernel)
//   [262144]  WvS  swizzled-tile layout
//   [393216]  OT   [d][hl]
// Swizzled tile: tile tau = n>>4 holds cols c=n&15, k=d at byte
//   o' = (c*256 + 2k) ^ ((c&7)<<4)  within the 4KB tile.
// All values scaled by -log2(e).
// ---------------------------------------------------------------------------
__global__ void prep_kernel(const float* __restrict__ Wq, const float* __restrict__ Wk,
                            const float* __restrict__ Wv, const float* __restrict__ O,
                            unsigned short* __restrict__ ws16) {
  const float NS = -LOG2E;
  int tid = blockIdx.x * 256 + threadIdx.x;
  for (int j = tid; j < 4 * 131072; j += 512 * 256) {
    int which = j >> 17;
    int i = j & 131071;
    float val;
    if (which == 0 || which == 2) {        // WqS / WvS, swizzled-tile
      const float* W = (which == 0) ? Wq : Wv;
      int tau = i >> 11;                   // 2048 elems per tile
      int op = (i & 2047) * 2;             // swizzled byte offset in tile
      int c = op >> 8;                     // col (bits 8-11, XOR-invariant)
      int o = op ^ ((c & 7) << 4);         // natural byte offset
      int k = (o & 255) >> 1;
      int n = tau * 16 + c;
      int h = n >> 7, lidx = n & 127;
      val = W[h * 16384 + k * 128 + lidx];
    } else if (which == 1) {               // WkT linear [n][d]
      int n = i >> 7, d = i & 127;
      int h = n >> 7, lidx = n & 127;
      val = Wk[h * 16384 + d * 128 + lidx];
    } else {                               // OT [d][hl]
      int n = i >> 10, k = i & 1023;
      val = O[k * 128 + n];
    }
    ws16[j] = f2h(val * NS);
  }
}

// ---------------------------------------------------------------------------
// kw_all[b][n] = sigmoid(origin_b . Wk[:,n]) * Ws_flat[n]   (fp16)
// grid (64, 4): 32 batches x 256 n per block -> 256 blocks (full CU cover)
// ---------------------------------------------------------------------------
__global__ __launch_bounds__(256, 2) void kw_kernel(
    const float* __restrict__ x, const float* __restrict__ Ws,
    const unsigned short* __restrict__ WkT, unsigned short* __restrict__ kw_all) {
  __shared__ __align__(16) char lds[8192];
  const int tid = threadIdx.x;
  const int b0 = blockIdx.x * 32;
  for (int i = tid; i < 1024; i += 256) {
    int row = i >> 5, c4 = i & 31;
    const float4 v = *(const float4*)(x + (size_t)(b0 + row) * 6400 + c4 * 4);
    uint2 pk;
    pk.x = (unsigned)f2h(v.x) | ((unsigned)f2h(v.y) << 16);
    pk.y = (unsigned)f2h(v.z) | ((unsigned)f2h(v.w) << 16);
    *(uint2*)(lds + row * 256 + ((c4 * 8) ^ ((row & 7) << 4))) = pk;
  }
  __syncthreads();
  const int w = tid >> 6, l = tid & 63, l15 = l & 15, l4 = l >> 4;
  f16x8 af[2][4];
#pragma unroll
  for (int mt = 0; mt < 2; ++mt)
#pragma unroll
    for (int kt = 0; kt < 4; ++kt) {
      int row = mt * 16 + l15;
      int c = kt * 64 + l4 * 16;
      af[mt][kt] = *(const f16x8*)(lds + row * 256 + (c ^ ((row & 7) << 4)));
    }
  const f16x8* B8 = (const f16x8*)WkT;
  for (int nt = 0; nt < 4; ++nt) {
    const int n0 = blockIdx.y * 256 + w * 64 + nt * 16;
    f16x8 bfr[4];
#pragma unroll
    for (int kt = 0; kt < 4; ++kt) bfr[kt] = B8[(size_t)(n0 + l15) * 16 + kt * 4 + l4];
    f32x4 acc[2];
#pragma unroll
    for (int mt = 0; mt < 2; ++mt) acc[mt] = (f32x4){0.f, 0.f, 0.f, 0.f};
#pragma unroll
    for (int mt = 0; mt < 2; ++mt)
#pragma unroll
      for (int kt = 0; kt < 4; ++kt)
        acc[mt] = __builtin_amdgcn_mfma_f32_16x16x32_f16(af[mt][kt], bfr[kt], acc[mt], 0, 0, 0);
    const float wsv = Ws[n0 + l15];
#pragma unroll
    for (int mt = 0; mt < 2; ++mt)
#pragma unroll
      for (int r = 0; r < 4; ++r) {
        int row = b0 + mt * 16 + l4 * 4 + r;
        kw_all[(size_t)row * 1024 + n0 + l15] = f2h(sig_scaled(acc[mt][r]) * wsv);
      }
  }
}

// ---------------------------------------------------------------------------
// fused: 1 batch/block, 4 waves. Wave w: cols w*256..+255 (heads 2w,2w+1).
// 2-tile software pipeline: iter t = {DMA(t+2), MFMA(t+1)->alt acc, POST(t)}.
// ---------------------------------------------------------------------------
__global__ __launch_bounds__(256, 3) void fused_kernel(
    const float* __restrict__ x,
    const unsigned short* __restrict__ WqS, const unsigned short* __restrict__ WvS,
    const unsigned short* __restrict__ kw_all, unsigned short* __restrict__ res_all) {
  // bytes [0,49152): 4 waves x 3 x 4KB weight slots (wave w: base w*12288).
  // bytes [0,16384) double as x staging during the prologue.
  __shared__ __align__(16) char lds[49152];
  __shared__ __align__(16) unsigned short kw16[1024];
  const int tid = threadIdx.x;
  const int b = blockIdx.x;
  const int w = tid >> 6, l = tid & 63, l15 = l & 15, l4 = l >> 4;
  const int ncol = w * 256;

  // ---- stage x_b (fp16, XOR-swizzled, rows 50..63 zero) + kw16 ----
  const float* xb = x + (size_t)b * 6400;
#pragma unroll
  for (int j = 0; j < 8; ++j) {
    int idx = tid + j * 256;          // 0..2047 = 64 rows x 32 float4
    int row = idx >> 5, c4 = idx & 31;
    uint2 pk = {0u, 0u};
    if (row < 50) {
      const float4 v = *(const float4*)(xb + row * 128 + c4 * 4);
      pk.x = (unsigned)f2h(v.x) | ((unsigned)f2h(v.y) << 16);
      pk.y = (unsigned)f2h(v.z) | ((unsigned)f2h(v.w) << 16);
    }
    *(uint2*)(lds + row * 256 + ((c4 * 8) ^ ((row & 7) << 4))) = pk;
  }
  *(ushort4*)(kw16 + tid * 4) =
      *(const ushort4*)(kw_all + (size_t)b * 1024 + tid * 4);
  __syncthreads();

  // ---- af: 16 frags (all 64 rows), register-resident for the block ----
  f16x8 af[4][4];
#pragma unroll
  for (int mt = 0; mt < 4; ++mt)
#pragma unroll
    for (int kt = 0; kt < 4; ++kt) {
      int row = mt * 16 + l15;
      int c = kt * 64 + l4 * 16;
      af[mt][kt] = *(const f16x8*)(lds + row * 256 + (c ^ ((row & 7) << 4)));
    }
  __syncthreads();   // all waves done reading x before DMA overwrites lds

  char* slotb = lds + w * 12288;     // 3-slot ring, 4KB each

  // load+MFMA one tile from slot cs into acc (half-K bf staging)
  auto LDMFMA = [&](const char* cs, f32x4* acc) {
#pragma unroll
    for (int mt = 0; mt < 4; ++mt) acc[mt] = (f32x4){0.f, 0.f, 0.f, 0.f};
    f16x8 bf0, bf1;
    {
      int o0 = (l15 * 256 + 0 * 64 + l4 * 16) ^ ((l15 & 7) << 4);
      int o1 = (l15 * 256 + 1 * 64 + l4 * 16) ^ ((l15 & 7) << 4);
      bf0 = *(const f16x8*)(cs + o0);
      bf1 = *(const f16x8*)(cs + o1);
    }
#pragma unroll
    for (int mt = 0; mt < 4; ++mt)
      acc[mt] = __builtin_amdgcn_mfma_f32_16x16x32_f16(af[mt][0], bf0, acc[mt], 0, 0, 0);
#pragma unroll
    for (int mt = 0; mt < 4; ++mt)
      acc[mt] = __builtin_amdgcn_mfma_f32_16x16x32_f16(af[mt][1], bf1, acc[mt], 0, 0, 0);
    {
      int o2 = (l15 * 256 + 2 * 64 + l4 * 16) ^ ((l15 & 7) << 4);
      int o3 = (l15 * 256 + 3 * 64 + l4 * 16) ^ ((l15 & 7) << 4);
      bf0 = *(const f16x8*)(cs + o2);
      bf1 = *(const f16x8*)(cs + o3);
    }
#pragma unroll
    for (int mt = 0; mt < 4; ++mt)
      acc[mt] = __builtin_amdgcn_mfma_f32_16x16x32_f16(af[mt][2], bf0, acc[mt], 0, 0, 0);
#pragma unroll
    for (int mt = 0; mt < 4; ++mt)
      acc[mt] = __builtin_amdgcn_mfma_f32_16x16x32_f16(af[mt][3], bf1, acc[mt], 0, 0, 0);
  };

  float pa[4][4];   // Q phase: score accumulator; after softmax: attn weights
#pragma unroll
  for (int mt = 0; mt < 4; ++mt)
#pragma unroll
    for (int r = 0; r < 4; ++r) pa[mt][r] = 0.f;

  // post-process tile t's accumulator (sigmoid / score / softmax / V-reduce)
  auto POST = [&](int t, f32x4* acc) {
    const int nt = (t & 7) + ((t >> 4) << 3);
    if (((t >> 3) & 1) == 0) {
      // ---- Q phase ----
      const float kwv = h2f(kw16[ncol + nt * 16 + l15]);
#pragma unroll
      for (int mt = 0; mt < 4; ++mt)
#pragma unroll
        for (int r = 0; r < 4; ++r) {
          if (mt < 3 || r < 2)   // rows for mt==3,r>=2 are all >= 50
            pa[mt][r] = fmaf(sig_scaled(acc[mt][r]), kwv, pa[mt][r]);
        }
      if ((t & 7) == 7) {
        // reduce over the 16 cols spread across l15 lanes
#pragma unroll
        for (int mt = 0; mt < 4; ++mt)
#pragma unroll
          for (int r = 0; r < 4; ++r) {
            if (mt == 3 && r >= 2) continue;
            float v = pa[mt][r];
            v += __shfl_xor(v, 1);
            v += __shfl_xor(v, 2);
            v += __shfl_xor(v, 4);
            v += __shfl_xor(v, 8);
            pa[mt][r] = v;          // score[row = mt*16 + l4*4 + r]
          }
        // in-register softmax over rows (mask rows >= 50)
        float m = -3.0e38f;
#pragma unroll
        for (int mt = 0; mt < 4; ++mt)
#pragma unroll
          for (int r = 0; r < 4; ++r) {
            if (mt == 3 && r >= 2) continue;
            int row = mt * 16 + l4 * 4 + r;
            m = fmaxf(m, (row < 50) ? pa[mt][r] : -3.0e38f);
          }
        m = fmaxf(m, __shfl_xor(m, 16));
        m = fmaxf(m, __shfl_xor(m, 32));
        float tsum = 0.f;
#pragma unroll
        for (int mt = 0; mt < 4; ++mt)
#pragma unroll
          for (int r = 0; r < 4; ++r) {
            int row = mt * 16 + l4 * 4 + r;
            float e = (row < 50 && !(mt == 3 && r >= 2))
                          ? fexp2((pa[mt][r] - m) * LOG2E) : 0.f;
            pa[mt][r] = e;
            tsum += e;
          }
        tsum += __shfl_xor(tsum, 16);
        tsum += __shfl_xor(tsum, 32);
        const float rs = frcp(tsum);
#pragma unroll
        for (int mt = 0; mt < 4; ++mt)
#pragma unroll
          for (int r = 0; r < 4; ++r) pa[mt][r] *= rs;
      }
    } else {
      // ---- V phase: res[col] = sum_rows attn[row] * sigmoid(v[row,col]) ----
      float part = 0.f;
#pragma unroll
      for (int mt = 0; mt < 4; ++mt)
#pragma unroll
        for (int r = 0; r < 4; ++r) {
          if (mt < 3 || r < 2)
            part = fmaf(pa[mt][r], sig_scaled(acc[mt][r]), part);
        }
      part += __shfl_xor(part, 16);
      part += __shfl_xor(part, 32);
      if (l < 16)
        res_all[(size_t)b * 1024 + ncol + nt * 16 + l15] = f2h(part);
      if (t == 15) {
        // reset accumulator for Q-hi
#pragma unroll
        for (int mt = 0; mt < 4; ++mt)
#pragma unroll
          for (int r = 0; r < 4; ++r) pa[mt][r] = 0.f;
      }
    }
  };

  // ---- prologue: DMA tiles 0,1; compute tile 0 into accA ----
  {
    const char* s0 = (const char*)WqS + (size_t)(ncol >> 4) * 4096 + l * 16;
    dma16(s0, slotb);
    dma16(s0 + 1024, slotb + 1024);
    dma16(s0 + 2048, slotb + 2048);
    dma16(s0 + 3072, slotb + 3072);
    const char* s1 = s0 + 4096;
    char* n1 = slotb + 4096;
    dma16(s1, n1);
    dma16(s1 + 1024, n1 + 1024);
    dma16(s1 + 2048, n1 + 2048);
    dma16(s1 + 3072, n1 + 3072);
  }
  f32x4 accA[4], accB[4];
  asm volatile("s_waitcnt vmcnt(4)" ::: "memory");
  __builtin_amdgcn_s_setprio(1);
  LDMFMA(slotb, accA);
  __builtin_amdgcn_s_setprio(0);

#pragma unroll
  for (int t = 0; t < 32; ++t) {
    // ---- issue DMA for tile t+2 ----
    if (t + 2 < 32) {
      const int t2 = t + 2;
      const int nt2 = (t2 & 7) + ((t2 >> 4) << 3);
      const unsigned short* W2 = ((t2 >> 3) & 1) ? WvS : WqS;
      const char* s = (const char*)W2 + (size_t)((ncol >> 4) + nt2) * 4096 + l * 16;
      char* nslot = slotb + (t2 % 3) * 4096;
      dma16(s, nslot);
      dma16(s + 1024, nslot + 1024);
      dma16(s + 2048, nslot + 2048);
      dma16(s + 3072, nslot + 3072);
    }
    // ---- MFMA tile t+1 into the alternate accumulator ----
    if (t + 1 < 32) {
      if (t + 2 < 32) {
        asm volatile("s_waitcnt vmcnt(4)" ::: "memory");
      } else {
        asm volatile("s_waitcnt vmcnt(0)" ::: "memory");
      }
      const char* cs = slotb + ((t + 1) % 3) * 4096;
      __builtin_amdgcn_s_setprio(1);
      if (((t + 1) & 1) == 0) LDMFMA(cs, accA); else LDMFMA(cs, accB);
      __builtin_amdgcn_s_setprio(0);
    }
    // ---- post-process tile t (overlaps tile t+1's MFMA execution) ----
    if ((t & 1) == 0) POST(t, accA); else POST(t, accB);
  }
}

// ---------------------------------------------------------------------------
// out[b][d] = sigmoid(res[b,:] . O[:,d]) + x[b][0][d]
// grid (128, 2): 16 rows x 64 cols per block -> 256 blocks (full CU cover)
// ---------------------------------------------------------------------------
__global__ __launch_bounds__(256, 4) void out_kernel(
    const unsigned short* __restrict__ res_all, const unsigned short* __restrict__ OT,
    const float* __restrict__ x, float* __restrict__ out) {
  const int tid = threadIdx.x;
  const int w = tid >> 6, l = tid & 63, l15 = l & 15, l4 = l >> 4;
  const int b0 = blockIdx.x * 16;
  const int n0 = blockIdx.y * 64 + w * 16;
  const f16x8* A8 = (const f16x8*)res_all;
  const f16x8* B8 = (const f16x8*)OT;
  f32x4 acc = (f32x4){0.f, 0.f, 0.f, 0.f};
#pragma unroll 4
  for (int kt = 0; kt < 32; ++kt) {
    f16x8 a = A8[(size_t)(b0 + l15) * 128 + kt * 4 + l4];
    f16x8 bq = B8[(size_t)(n0 + l15) * 128 + kt * 4 + l4];
    acc = __builtin_amdgcn_mfma_f32_16x16x32_f16(a, bq, acc, 0, 0, 0);
  }
#pragma unroll
  for (int r = 0; r < 4; ++r) {
    int row = b0 + l4 * 4 + r;
    int col = n0 + l15;
    out[(size_t)row * 128 + col] = sig_scaled(acc[r]) + x[(size_t)row * 6400 + col];
  }
}

extern "C" void kernel_launch(void* const* d_in, const int* in_sizes, int n_in,
                              void* d_out, int out_size, void* d_ws, size_t ws_size,
                              hipStream_t stream) {
  const float* x  = (const float*)d_in[0];
  const float* Wq = (const float*)d_in[1];
  const float* Wk = (const float*)d_in[2];
  const float* Wv = (const float*)d_in[3];
  const float* Ws = (const float*)d_in[4];
  const float* O  = (const float*)d_in[5];
  float* out = (float*)d_out;

  unsigned short* ws16    = (unsigned short*)d_ws;
  unsigned short* WqS     = ws16;                    // swizzled tiles
  unsigned short* WkT     = ws16 + 131072;           // linear (kw_kernel)
  unsigned short* WvS     = ws16 + 262144;           // swizzled tiles
  unsigned short* OT      = ws16 + 393216;
  unsigned short* kw_all  = ws16 + 524288;           // 2048*1024 fp16
  unsigned short* res_all = ws16 + 524288 + 2097152; // 2048*1024 fp16

  prep_kernel<<<512, 256, 0, stream>>>(Wq, Wk, Wv, O, ws16);
  kw_kernel<<<dim3(64, 4), 256, 0, stream>>>(x, Ws, WkT, kw_all);
  fused_kernel<<<2048, 256, 0, stream>>>(x, WqS, WvS, kw_all, res_all);
  out_kernel<<<dim3(128, 2), 256, 0, stream>>>(res_all, OT, x, out);
}

// Round 14
// 116.951 us; speedup vs baseline: 1.1350x; 1.1350x over previous
//
#include <hip/hip_runtime.h>
#include <hip/hip_bf16.h>

// Shapes (fixed): B=2048, S=50, D=128, H=8, L=128, HL=1024.
// R14 = exact revert to R12 (best verified: 117.6 us total).
// R13's 2-tile software pipeline regressed (104 -> 130 us fused): computing
// tile t+1 in iteration t forces vmcnt(4) "t+1 landed" with only 1 iteration
// of DMA slack, vs R12's vmcnt(8) 2-tile slack. Wave-level TLP already
// provides the MFMA/VALU overlap the manual pipeline tried to create.

typedef _Float16 f16x8 __attribute__((ext_vector_type(8)));
typedef float f32x4 __attribute__((ext_vector_type(4)));

#define LOG2E 1.44269504088896340736f

__device__ __forceinline__ unsigned short f2h(float f) {
  _Float16 h = (_Float16)f;
  return __builtin_bit_cast(unsigned short, h);
}
__device__ __forceinline__ float h2f(unsigned short s) {
  return (float)__builtin_bit_cast(_Float16, s);
}
__device__ __forceinline__ float fexp2(float x) {
#if __has_builtin(__builtin_amdgcn_exp2f)
  return __builtin_amdgcn_exp2f(x);
#else
  return exp2f(x);
#endif
}
__device__ __forceinline__ float frcp(float x) {
#if __has_builtin(__builtin_amdgcn_rcpf)
  return __builtin_amdgcn_rcpf(x);
#else
  return 1.0f / x;
#endif
}
__device__ __forceinline__ float sig_scaled(float a) {  // a = -log2e * z
  return frcp(1.0f + fexp2(a));
}

// async global -> LDS, 16B per lane; lds dest must be wave-uniform base.
__device__ __forceinline__ void dma16(const void* g, void* l) {
  __builtin_amdgcn_global_load_lds(
      (const __attribute__((address_space(1))) unsigned int*)g,
      (__attribute__((address_space(3))) unsigned int*)(unsigned int)(unsigned long long)l,
      16, 0, 0);
}

// ---------------------------------------------------------------------------
// prep: ws16 layout (elements):
//   [0]       WqS  swizzled-tile layout (64 tiles x 2048 elems)
//   [131072]  WkT  linear [n][d] (for kw_kernel)
//   [262144]  WvS  swizzled-tile layout
//   [393216]  OT   [d][hl]
// Swizzled tile: tile tau = n>>4 holds cols c=n&15, k=d at byte
//   o' = (c*256 + 2k) ^ ((c&7)<<4)  within the 4KB tile.
// All values scaled by -log2(e).
// ---------------------------------------------------------------------------
__global__ void prep_kernel(const float* __restrict__ Wq, const float* __restrict__ Wk,
                            const float* __restrict__ Wv, const float* __restrict__ O,
                            unsigned short* __restrict__ ws16) {
  const float NS = -LOG2E;
  int tid = blockIdx.x * 256 + threadIdx.x;
  for (int j = tid; j < 4 * 131072; j += 512 * 256) {
    int which = j >> 17;
    int i = j & 131071;
    float val;
    if (which == 0 || which == 2) {        // WqS / WvS, swizzled-tile
      const float* W = (which == 0) ? Wq : Wv;
      int tau = i >> 11;                   // 2048 elems per tile
      int op = (i & 2047) * 2;             // swizzled byte offset in tile
      int c = op >> 8;                     // col (bits 8-11, XOR-invariant)
      int o = op ^ ((c & 7) << 4);         // natural byte offset
      int k = (o & 255) >> 1;
      int n = tau * 16 + c;
      int h = n >> 7, lidx = n & 127;
      val = W[h * 16384 + k * 128 + lidx];
    } else if (which == 1) {               // WkT linear [n][d]
      int n = i >> 7, d = i & 127;
      int h = n >> 7, lidx = n & 127;
      val = Wk[h * 16384 + d * 128 + lidx];
    } else {                               // OT [d][hl]
      int n = i >> 10, k = i & 1023;
      val = O[k * 128 + n];
    }
    ws16[j] = f2h(val * NS);
  }
}

// ---------------------------------------------------------------------------
// kw_all[b][n] = sigmoid(origin_b . Wk[:,n]) * Ws_flat[n]   (fp16)
// grid (64, 4): 32 batches x 256 n per block -> 256 blocks (full CU cover)
// ---------------------------------------------------------------------------
__global__ __launch_bounds__(256, 2) void kw_kernel(
    const float* __restrict__ x, const float* __restrict__ Ws,
    const unsigned short* __restrict__ WkT, unsigned short* __restrict__ kw_all) {
  __shared__ __align__(16) char lds[8192];
  const int tid = threadIdx.x;
  const int b0 = blockIdx.x * 32;
  for (int i = tid; i < 1024; i += 256) {
    int row = i >> 5, c4 = i & 31;
    const float4 v = *(const float4*)(x + (size_t)(b0 + row) * 6400 + c4 * 4);
    uint2 pk;
    pk.x = (unsigned)f2h(v.x) | ((unsigned)f2h(v.y) << 16);
    pk.y = (unsigned)f2h(v.z) | ((unsigned)f2h(v.w) << 16);
    *(uint2*)(lds + row * 256 + ((c4 * 8) ^ ((row & 7) << 4))) = pk;
  }
  __syncthreads();
  const int w = tid >> 6, l = tid & 63, l15 = l & 15, l4 = l >> 4;
  f16x8 af[2][4];
#pragma unroll
  for (int mt = 0; mt < 2; ++mt)
#pragma unroll
    for (int kt = 0; kt < 4; ++kt) {
      int row = mt * 16 + l15;
      int c = kt * 64 + l4 * 16;
      af[mt][kt] = *(const f16x8*)(lds + row * 256 + (c ^ ((row & 7) << 4)));
    }
  const f16x8* B8 = (const f16x8*)WkT;
  for (int nt = 0; nt < 4; ++nt) {
    const int n0 = blockIdx.y * 256 + w * 64 + nt * 16;
    f16x8 bfr[4];
#pragma unroll
    for (int kt = 0; kt < 4; ++kt) bfr[kt] = B8[(size_t)(n0 + l15) * 16 + kt * 4 + l4];
    f32x4 acc[2];
#pragma unroll
    for (int mt = 0; mt < 2; ++mt) acc[mt] = (f32x4){0.f, 0.f, 0.f, 0.f};
#pragma unroll
    for (int mt = 0; mt < 2; ++mt)
#pragma unroll
      for (int kt = 0; kt < 4; ++kt)
        acc[mt] = __builtin_amdgcn_mfma_f32_16x16x32_f16(af[mt][kt], bfr[kt], acc[mt], 0, 0, 0);
    const float wsv = Ws[n0 + l15];
#pragma unroll
    for (int mt = 0; mt < 2; ++mt)
#pragma unroll
      for (int r = 0; r < 4; ++r) {
        int row = b0 + mt * 16 + l4 * 4 + r;
        kw_all[(size_t)row * 1024 + n0 + l15] = f2h(sig_scaled(acc[mt][r]) * wsv);
      }
  }
}

// ---------------------------------------------------------------------------
// fused: 1 batch/block, 4 waves. Wave w: cols w*256..+255 (heads 2w,2w+1),
// all 64 rows. Flat 32-tile stream: Q-lo(8) V-lo(8) Q-hi(8) V-hi(8).
// Weight tile t+2 DMA'd into wave-private 3-slot ring while computing t.
// kw in registers (16 fp32), loaded in prologue under staging latency.
// ---------------------------------------------------------------------------
__global__ __launch_bounds__(256, 3) void fused_kernel(
    const float* __restrict__ x,
    const unsigned short* __restrict__ WqS, const unsigned short* __restrict__ WvS,
    const unsigned short* __restrict__ kw_all, unsigned short* __restrict__ res_all) {
  // bytes [0,49152): 4 waves x 3 x 4KB weight slots (wave w: base w*12288).
  // bytes [0,16384) double as x staging during the prologue.
  __shared__ __align__(16) char lds[49152];
  const int tid = threadIdx.x;
  const int b = blockIdx.x;
  const int w = tid >> 6, l = tid & 63, l15 = l & 15, l4 = l >> 4;
  const int ncol = w * 256;

  // ---- issue kw loads first (latency hidden under x staging) ----
  unsigned short kwr[16];
  {
    const unsigned short* kwp = kw_all + (size_t)b * 1024 + ncol + l15;
#pragma unroll
    for (int nt = 0; nt < 16; ++nt) kwr[nt] = kwp[nt * 16];
  }

  // ---- stage x_b (fp16, XOR-swizzled, rows 50..63 zero) ----
  const float* xb = x + (size_t)b * 6400;
#pragma unroll
  for (int j = 0; j < 8; ++j) {
    int idx = tid + j * 256;          // 0..2047 = 64 rows x 32 float4
    int row = idx >> 5, c4 = idx & 31;
    uint2 pk = {0u, 0u};
    if (row < 50) {
      const float4 v = *(const float4*)(xb + row * 128 + c4 * 4);
      pk.x = (unsigned)f2h(v.x) | ((unsigned)f2h(v.y) << 16);
      pk.y = (unsigned)f2h(v.z) | ((unsigned)f2h(v.w) << 16);
    }
    *(uint2*)(lds + row * 256 + ((c4 * 8) ^ ((row & 7) << 4))) = pk;
  }
  __syncthreads();

  // ---- af: 16 frags (all 64 rows), register-resident for the block ----
  f16x8 af[4][4];
#pragma unroll
  for (int mt = 0; mt < 4; ++mt)
#pragma unroll
    for (int kt = 0; kt < 4; ++kt) {
      int row = mt * 16 + l15;
      int c = kt * 64 + l4 * 16;
      af[mt][kt] = *(const f16x8*)(lds + row * 256 + (c ^ ((row & 7) << 4)));
    }
  // ---- convert kw to fp32 regs (loads long since landed) ----
  float kwf[16];
#pragma unroll
  for (int nt = 0; nt < 16; ++nt) kwf[nt] = h2f(kwr[nt]);
  __syncthreads();   // all waves done reading x before DMA overwrites lds

  char* slotb = lds + w * 12288;     // 3-slot ring, 4KB each

  // ---- prologue: DMA tiles 0 (Q nt0) and 1 (Q nt1) ----
  {
    const char* s0 = (const char*)WqS + (size_t)(ncol >> 4) * 4096 + l * 16;
    dma16(s0, slotb);
    dma16(s0 + 1024, slotb + 1024);
    dma16(s0 + 2048, slotb + 2048);
    dma16(s0 + 3072, slotb + 3072);
    const char* s1 = s0 + 4096;
    char* n1 = slotb + 4096;
    dma16(s1, n1);
    dma16(s1 + 1024, n1 + 1024);
    dma16(s1 + 2048, n1 + 2048);
    dma16(s1 + 3072, n1 + 3072);
  }

  float pa[4][4];   // Q phase: score accumulator; after reduce: attn weights
#pragma unroll
  for (int mt = 0; mt < 4; ++mt)
#pragma unroll
    for (int r = 0; r < 4; ++r) pa[mt][r] = 0.f;

#pragma unroll
  for (int t = 0; t < 32; ++t) {
    const int nt = (t & 7) + ((t >> 4) << 3);
    char* cslot = slotb + (t % 3) * 4096;
    if (t < 30) {
      const int t2 = t + 2;
      const int nt2 = (t2 & 7) + ((t2 >> 4) << 3);
      const unsigned short* W2 = ((t2 >> 3) & 1) ? WvS : WqS;
      const char* s = (const char*)W2 + (size_t)((ncol >> 4) + nt2) * 4096 + l * 16;
      char* nslot = slotb + (t2 % 3) * 4096;
      dma16(s, nslot);
      dma16(s + 1024, nslot + 1024);
      dma16(s + 2048, nslot + 2048);
      dma16(s + 3072, nslot + 3072);
      asm volatile("s_waitcnt vmcnt(8)" ::: "memory");
    } else if (t == 30) {
      asm volatile("s_waitcnt vmcnt(4)" ::: "memory");
    } else {
      asm volatile("s_waitcnt vmcnt(0)" ::: "memory");
    }
    __builtin_amdgcn_s_setprio(1);
    f32x4 acc[4];
#pragma unroll
    for (int mt = 0; mt < 4; ++mt) acc[mt] = (f32x4){0.f, 0.f, 0.f, 0.f};
    // ---- half-K staging: only 2 bf fragments live at a time ----
    {
      f16x8 bf0, bf1;
      {
        int o0 = (l15 * 256 + 0 * 64 + l4 * 16) ^ ((l15 & 7) << 4);
        int o1 = (l15 * 256 + 1 * 64 + l4 * 16) ^ ((l15 & 7) << 4);
        bf0 = *(const f16x8*)(cslot + o0);
        bf1 = *(const f16x8*)(cslot + o1);
      }
#pragma unroll
      for (int mt = 0; mt < 4; ++mt)
        acc[mt] = __builtin_amdgcn_mfma_f32_16x16x32_f16(af[mt][0], bf0, acc[mt], 0, 0, 0);
#pragma unroll
      for (int mt = 0; mt < 4; ++mt)
        acc[mt] = __builtin_amdgcn_mfma_f32_16x16x32_f16(af[mt][1], bf1, acc[mt], 0, 0, 0);
      {
        int o2 = (l15 * 256 + 2 * 64 + l4 * 16) ^ ((l15 & 7) << 4);
        int o3 = (l15 * 256 + 3 * 64 + l4 * 16) ^ ((l15 & 7) << 4);
        bf0 = *(const f16x8*)(cslot + o2);
        bf1 = *(const f16x8*)(cslot + o3);
      }
#pragma unroll
      for (int mt = 0; mt < 4; ++mt)
        acc[mt] = __builtin_amdgcn_mfma_f32_16x16x32_f16(af[mt][2], bf0, acc[mt], 0, 0, 0);
#pragma unroll
      for (int mt = 0; mt < 4; ++mt)
        acc[mt] = __builtin_amdgcn_mfma_f32_16x16x32_f16(af[mt][3], bf1, acc[mt], 0, 0, 0);
    }
    __builtin_amdgcn_s_setprio(0);

    if (((t >> 3) & 1) == 0) {
      // ---- Q phase ----
      const float kwv = kwf[nt];
#pragma unroll
      for (int mt = 0; mt < 4; ++mt)
#pragma unroll
        for (int r = 0; r < 4; ++r) {
          if (mt < 3 || r < 2)   // rows for mt==3,r>=2 are all >= 50
            pa[mt][r] = fmaf(sig_scaled(acc[mt][r]), kwv, pa[mt][r]);
        }
      if ((t & 7) == 7) {
        // reduce over the 16 cols spread across l15 lanes
#pragma unroll
        for (int mt = 0; mt < 4; ++mt)
#pragma unroll
          for (int r = 0; r < 4; ++r) {
            if (mt == 3 && r >= 2) continue;
            float v = pa[mt][r];
            v += __shfl_xor(v, 1);
            v += __shfl_xor(v, 2);
            v += __shfl_xor(v, 4);
            v += __shfl_xor(v, 8);
            pa[mt][r] = v;          // score[row = mt*16 + l4*4 + r]
          }
        // in-register softmax over rows (mask rows >= 50)
        float m = -3.0e38f;
#pragma unroll
        for (int mt = 0; mt < 4; ++mt)
#pragma unroll
          for (int r = 0; r < 4; ++r) {
            if (mt == 3 && r >= 2) continue;
            int row = mt * 16 + l4 * 4 + r;
            m = fmaxf(m, (row < 50) ? pa[mt][r] : -3.0e38f);
          }
        m = fmaxf(m, __shfl_xor(m, 16));
        m = fmaxf(m, __shfl_xor(m, 32));
        float tsum = 0.f;
#pragma unroll
        for (int mt = 0; mt < 4; ++mt)
#pragma unroll
          for (int r = 0; r < 4; ++r) {
            int row = mt * 16 + l4 * 4 + r;
            float e = (row < 50 && !(mt == 3 && r >= 2))
                          ? fexp2((pa[mt][r] - m) * LOG2E) : 0.f;
            pa[mt][r] = e;
            tsum += e;
          }
        tsum += __shfl_xor(tsum, 16);
        tsum += __shfl_xor(tsum, 32);
        const float rs = frcp(tsum);
#pragma unroll
        for (int mt = 0; mt < 4; ++mt)
#pragma unroll
          for (int r = 0; r < 4; ++r) pa[mt][r] *= rs;
      }
    } else {
      // ---- V phase: res[col] = sum_rows attn[row] * sigmoid(v[row,col]) ----
      float part = 0.f;
#pragma unroll
      for (int mt = 0; mt < 4; ++mt)
#pragma unroll
        for (int r = 0; r < 4; ++r) {
          if (mt < 3 || r < 2)
            part = fmaf(pa[mt][r], sig_scaled(acc[mt][r]), part);
        }
      part += __shfl_xor(part, 16);
      part += __shfl_xor(part, 32);
      if (l < 16)
        res_all[(size_t)b * 1024 + ncol + nt * 16 + l15] = f2h(part);
      if (t == 15) {
        // reset accumulator for Q-hi
#pragma unroll
        for (int mt = 0; mt < 4; ++mt)
#pragma unroll
          for (int r = 0; r < 4; ++r) pa[mt][r] = 0.f;
      }
    }
  }
}

// ---------------------------------------------------------------------------
// out[b][d] = sigmoid(res[b,:] . O[:,d]) + x[b][0][d]
// grid (128, 2): 16 rows x 64 cols per block -> 256 blocks (full CU cover)
// ---------------------------------------------------------------------------
__global__ __launch_bounds__(256, 4) void out_kernel(
    const unsigned short* __restrict__ res_all, const unsigned short* __restrict__ OT,
    const float* __restrict__ x, float* __restrict__ out) {
  const int tid = threadIdx.x;
  const int w = tid >> 6, l = tid & 63, l15 = l & 15, l4 = l >> 4;
  const int b0 = blockIdx.x * 16;
  const int n0 = blockIdx.y * 64 + w * 16;
  const f16x8* A8 = (const f16x8*)res_all;
  const f16x8* B8 = (const f16x8*)OT;
  f32x4 acc = (f32x4){0.f, 0.f, 0.f, 0.f};
#pragma unroll 4
  for (int kt = 0; kt < 32; ++kt) {
    f16x8 a = A8[(size_t)(b0 + l15) * 128 + kt * 4 + l4];
    f16x8 bq = B8[(size_t)(n0 + l15) * 128 + kt * 4 + l4];
    acc = __builtin_amdgcn_mfma_f32_16x16x32_f16(a, bq, acc, 0, 0, 0);
  }
#pragma unroll
  for (int r = 0; r < 4; ++r) {
    int row = b0 + l4 * 4 + r;
    int col = n0 + l15;
    out[(size_t)row * 128 + col] = sig_scaled(acc[r]) + x[(size_t)row * 6400 + col];
  }
}

extern "C" void kernel_launch(void* const* d_in, const int* in_sizes, int n_in,
                              void* d_out, int out_size, void* d_ws, size_t ws_size,
                              hipStream_t stream) {
  const float* x  = (const float*)d_in[0];
  const float* Wq = (const float*)d_in[1];
  const float* Wk = (const float*)d_in[2];
  const float* Wv = (const float*)d_in[3];
  const float* Ws = (const float*)d_in[4];
  const float* O  = (const float*)d_in[5];
  float* out = (float*)d_out;

  unsigned short* ws16    = (unsigned short*)d_ws;
  unsigned short* WqS     = ws16;                    // swizzled tiles
  unsigned short* WkT     = ws16 + 131072;           // linear (kw_kernel)
  unsigned short* WvS     = ws16 + 262144;           // swizzled tiles
  unsigned short* OT      = ws16 + 393216;
  unsigned short* kw_all  = ws16 + 524288;           // 2048*1024 fp16
  unsigned short* res_all = ws16 + 524288 + 2097152; // 2048*1024 fp16

  prep_kernel<<<512, 256, 0, stream>>>(Wq, Wk, Wv, O, ws16);
  kw_kernel<<<dim3(64, 4), 256, 0, stream>>>(x, Ws, WkT, kw_all);
  fused_kernel<<<2048, 256, 0, stream>>>(x, WqS, WvS, kw_all, res_all);
  out_kernel<<<dim3(128, 2), 256, 0, stream>>>(res_all, OT, x, out);
}